// Round 1
// baseline (441.090 us; speedup 1.0000x reference)
//
#include <hip/hip_runtime.h>

#define NEG_INF -9000000000000000.0f
#define ALPHA 0.2f

// wa[0:64]  = W @ a1   (a1 = a[0:64])
// wa[64:128]= W @ a2   (a2 = a[64:128])
__global__ void precompute_wa(const float* __restrict__ W, const float* __restrict__ a,
                              float* __restrict__ wa) {
    __shared__ float a_sh[128];
    int t = threadIdx.x; // 128 threads
    a_sh[t] = a[t];
    __syncthreads();
    if (t < 64) {
        float s1 = 0.f, s2 = 0.f;
        const float* row = W + t * 64;
#pragma unroll
        for (int h = 0; h < 64; ++h) {
            float w = row[h];
            s1 += w * a_sh[h];
            s2 += w * a_sh[64 + h];
        }
        wa[t] = s1;
        wa[64 + t] = s2;
    }
}

// One block per node n. 256 threads = 4 waves.
// Entity tile lives in REGISTERS only (no 16 KB LDS staging): thread t holds
// rows {16i + (t>>4)}, floats 4q..4q+3 (q = t&15), i = 0..3.
// Softmax is computed redundantly by all 4 waves (lane m <-> neighbor m),
// so only 2 barriers remain and no wave idles. LDS: 1.25 KB.
__global__ __launch_bounds__(256) void gat_kernel(
    const float* __restrict__ item, const float* __restrict__ ent_g,
    const int* __restrict__ adj, const float* __restrict__ wa,
    float* __restrict__ out)
{
    __shared__ float e_sh[64];
    __shared__ float red_sh[256];   // [wave][64 f]

    const int n = blockIdx.x;
    const int t = threadIdx.x;
    const int l = t & 63;      // lane within wave
    const int w = t >> 6;      // wave id
    const int q = t & 15;      // f-chunk id: this thread owns f = 4q..4q+3

    // ---- Issue ALL global loads up front (independent, overlap latency) ----
    // Entity tile: chunk c = i*256 + t -> one contiguous 4 KB per wave instruction.
    const float4* src4 = (const float4*)(ent_g + (size_t)n * 4096);
    float4 v[4];
#pragma unroll
    for (int i = 0; i < 4; ++i) v[i] = src4[i * 256 + t];

    const float4 w2   = ((const float4*)(wa + 64))[q];   // wa2 chunk (L2-hot)
    const int   adjv  = adj[(size_t)n * 64 + l];          // redundant x4 waves, L1-hot
    const float itemv = item[(size_t)n * 64 + l];         // redundant x4 waves, L1-hot
    const float wa1l  = wa[l];

    // ---- Per-row score partials -> e_sh (same mapping as before) ----
    // chunk c = i*256+t covers row m = i*16 + (t>>4), floats 4q..4q+3
#pragma unroll
    for (int i = 0; i < 4; ++i) {
        float p = v[i].x * w2.x + v[i].y * w2.y + v[i].z * w2.z + v[i].w * w2.w;
        p += __shfl_xor(p, 1);
        p += __shfl_xor(p, 2);
        p += __shfl_xor(p, 4);
        p += __shfl_xor(p, 8);   // reduced across the 16 lanes sharing row m
        if (q == 0) e_sh[i * 16 + (t >> 4)] = p;
    }

    // s1 = dot(item, wa1): every wave redundantly (64-lane butterfly)
    float s1 = itemv * wa1l;
#pragma unroll
    for (int k = 1; k < 64; k <<= 1) s1 += __shfl_xor(s1, k);

    __syncthreads();   // e_sh ready

    // ---- Softmax over 64 neighbors, all waves redundantly: lane m holds att[m] ----
    float e = s1 + e_sh[l];
    e = e > 0.f ? e : ALPHA * e;
    if (adjv <= 0) e = NEG_INF;
    float mx = e;
#pragma unroll
    for (int k = 1; k < 64; k <<= 1) mx = fmaxf(mx, __shfl_xor(mx, k));
    float ex = __expf(e - mx);
    float sm = ex;
#pragma unroll
    for (int k = 1; k < 64; k <<= 1) sm += __shfl_xor(sm, k);
    const float attw = ex / sm;   // lane m's attention weight

    // ---- Weighted sum straight from registers ----
    // Thread t needs att for its 4 rows: one bpermute each, then FMA into acc.
    float4 acc = {0.f, 0.f, 0.f, 0.f};
#pragma unroll
    for (int i = 0; i < 4; ++i) {
        const int row = i * 16 + (t >> 4);       // == i*16 + 4*w + (l>>4), in [0,64)
        const float ai = __shfl(attw, row);
        acc.x += ai * v[i].x;
        acc.y += ai * v[i].y;
        acc.z += ai * v[i].z;
        acc.w += ai * v[i].w;
    }

    // Reduce over the 4 row-subgroups sharing f-chunk q (lanes l, l^16, l^32, l^48)
    acc.x += __shfl_xor(acc.x, 16); acc.y += __shfl_xor(acc.y, 16);
    acc.z += __shfl_xor(acc.z, 16); acc.w += __shfl_xor(acc.w, 16);
    acc.x += __shfl_xor(acc.x, 32); acc.y += __shfl_xor(acc.y, 32);
    acc.z += __shfl_xor(acc.z, 32); acc.w += __shfl_xor(acc.w, 32);
    if (l < 16) ((float4*)red_sh)[w * 16 + l] = acc;   // wave partial, f = 4l..4l+3
    __syncthreads();

    // ---- out[f] = sum over 4 wave partials + item[f] (wave0 lane t holds item[t]) ----
    if (t < 64) {
        out[(size_t)n * 64 + t] =
            red_sh[t] + red_sh[64 + t] + red_sh[128 + t] + red_sh[192 + t] + itemv;
    }
}

extern "C" void kernel_launch(void* const* d_in, const int* in_sizes, int n_in,
                              void* d_out, int out_size, void* d_ws, size_t ws_size,
                              hipStream_t stream) {
    const float* item = (const float*)d_in[0];   // (N, 64)
    const float* ent  = (const float*)d_in[1];   // (N, 64, 64)
    const int*   adj  = (const int*)d_in[2];     // (N, 64)
    const float* W    = (const float*)d_in[3];   // (64, 64)
    const float* a    = (const float*)d_in[4];   // (128, 1)
    float* out = (float*)d_out;                  // (N, 64)
    float* wa  = (float*)d_ws;                   // 128 floats scratch

    const int N = in_sizes[0] / 64;

    precompute_wa<<<1, 128, 0, stream>>>(W, a, wa);
    gat_kernel<<<N, 256, 0, stream>>>(item, ent, adj, wa, out);
}